// Round 2
// baseline (8506.886 us; speedup 1.0000x reference)
//
#include <hip/hip_runtime.h>
#include <math.h>

#define HD 128
#define NNODES 50000
#define NEDGES 1000000
#define NGRAPH 512

enum { F_ACC = 1, F_SWISH = 2, F_RES = 4 };

__device__ __forceinline__ float swish_f(float v) {
    return v / (1.0f + __expf(-v));
}

// out[n,o] = post( sum_k A[n,k] * W[o*wld+k] + bias[o] ), rows tiled 64/block.
// lane = row; wave w computes outputs [32w, 32w+32). Weights are wave-uniform
// (scalar loads); A staged in LDS stride-129 (odd -> conflict-free); output
// transposed through LDS so stores coalesce.
__global__ __launch_bounds__(256) void node_mm_kernel(
    const float* __restrict__ A, const float* __restrict__ W, int wld,
    const float* __restrict__ bias, const float* __restrict__ res,
    float* __restrict__ out, int nrows, int flags)
{
    __shared__ float s_a[64 * 129];
    const int tid = threadIdx.x;
    const int ln = tid & 63;
    const int wv = tid >> 6;
    const int tile = blockIdx.x * 64;

    for (int i = tid; i < 64 * HD; i += 256) {
        int r = i >> 7, c = i & (HD - 1);
        int row = tile + r;
        if (row >= nrows) row = nrows - 1;
        s_a[r * 129 + c] = A[row * HD + c];
    }
    __syncthreads();

    const int o0 = wv * 32;
    float acc[32];
    #pragma unroll
    for (int oo = 0; oo < 32; ++oo) acc[oo] = 0.0f;

    for (int k = 0; k < HD; k += 4) {
        float a0 = s_a[ln * 129 + k + 0];
        float a1 = s_a[ln * 129 + k + 1];
        float a2 = s_a[ln * 129 + k + 2];
        float a3 = s_a[ln * 129 + k + 3];
        #pragma unroll
        for (int oo = 0; oo < 32; ++oo) {
            const float* wr = W + (o0 + oo) * wld + k;   // wave-uniform -> s_load
            acc[oo] += a0 * wr[0] + a1 * wr[1] + a2 * wr[2] + a3 * wr[3];
        }
    }
    __syncthreads();
    #pragma unroll
    for (int oo = 0; oo < 32; ++oo) s_a[ln * 129 + o0 + oo] = acc[oo];
    __syncthreads();

    for (int i = tid; i < 64 * HD; i += 256) {
        int r = i >> 7, c = i & (HD - 1);
        int row = tile + r;
        if (row < nrows) {
            float v = s_a[r * 129 + c];
            if (bias) v += bias[c];
            if (flags & F_ACC) v += out[row * HD + c];
            if (flags & F_SWISH) v = swish_f(v);
            if (flags & F_RES) v += res[row * HD + c];
            out[row * HD + c] = v;
        }
    }
}

// Fused edge pipeline for 64 edges/block:
//   mid1 = feat1 @ W1a^T (54->64), mid2 = feat2 @ W1b^T (18->64)   [mm-style]
//   e1 = mid1 @ W2a^T, e2 = mid2 @ W2b^T (64->128 each)            [regs+scalar W]
//   agg1[dst] += e1 * xw[src]; agg2[dst] += e2 * xw[src]           [coalesced atomics]
__global__ __launch_bounds__(256) void edge_kernel(
    const float* __restrict__ feat1, const float* __restrict__ feat2,
    const int* __restrict__ src, const int* __restrict__ dst,
    const float* __restrict__ xw,
    const float* __restrict__ w1a, const float* __restrict__ w2a,
    const float* __restrict__ w1b, const float* __restrict__ w2b,
    float* __restrict__ agg1, float* __restrict__ agg2)
{
    __shared__ float s_f[64 * 73];       // feat1 cols 0..53, feat2 cols 54..71
    __shared__ float s_m[64 * 133];      // mid1 cols 0..63, mid2 cols 64..127
    __shared__ float s_e[64][2][17];     // per-chunk edge outputs (16 o's + pad)

    const int tid = threadIdx.x;
    const int ln = tid & 63;
    const int wv = tid >> 6;
    const int bb = blockIdx.x * 64;

    for (int i = tid; i < 64 * 54; i += 256) {
        int r = i / 54, c = i - r * 54;
        s_f[r * 73 + c] = feat1[(bb + r) * 54 + c];
    }
    for (int i = tid; i < 64 * 18; i += 256) {
        int r = i / 18, c = i - r * 18;
        s_f[r * 73 + 54 + c] = feat2[(bb + r) * 18 + c];
    }
    __syncthreads();

    // ---- mid phase: lane = edge, wave wv owns mid outputs [16wv, 16wv+16)
    {
        const int o0 = wv * 16;
        float acc1[16], acc2[16];
        #pragma unroll
        for (int oo = 0; oo < 16; ++oo) { acc1[oo] = 0.f; acc2[oo] = 0.f; }
        for (int k = 0; k < 54; ++k) {
            float a = s_f[ln * 73 + k];
            #pragma unroll
            for (int oo = 0; oo < 16; ++oo)
                acc1[oo] += a * w1a[(o0 + oo) * 54 + k];
        }
        for (int k = 0; k < 18; ++k) {
            float a = s_f[ln * 73 + 54 + k];
            #pragma unroll
            for (int oo = 0; oo < 16; ++oo)
                acc2[oo] += a * w1b[(o0 + oo) * 18 + k];
        }
        #pragma unroll
        for (int oo = 0; oo < 16; ++oo) {
            s_m[ln * 133 + o0 + oo] = acc1[oo];
            s_m[ln * 133 + 64 + o0 + oo] = acc2[oo];
        }
    }
    __syncthreads();

    // ---- pull this lane's edge mids into registers
    float m1[64], m2[64];
    #pragma unroll
    for (int k = 0; k < 64; ++k) {
        m1[k] = s_m[ln * 133 + k];
        m2[k] = s_m[ln * 133 + 64 + k];
    }

    // ---- e-phase + scatter in 8 chunks of 16 outputs
    for (int c4 = 0; c4 < 8; ++c4) {
        for (int oo = 0; oo < 4; ++oo) {
            const int o = c4 * 16 + wv * 4 + oo;
            const float* wa = w2a + o * 64;   // wave-uniform -> s_load
            const float* wb = w2b + o * 64;
            float p0 = 0, p1 = 0, p2 = 0, p3 = 0;
            float q0 = 0, q1 = 0, q2 = 0, q3 = 0;
            #pragma unroll
            for (int k = 0; k < 64; k += 4) {
                p0 += m1[k + 0] * wa[k + 0]; p1 += m1[k + 1] * wa[k + 1];
                p2 += m1[k + 2] * wa[k + 2]; p3 += m1[k + 3] * wa[k + 3];
                q0 += m2[k + 0] * wb[k + 0]; q1 += m2[k + 1] * wb[k + 1];
                q2 += m2[k + 2] * wb[k + 2]; q3 += m2[k + 3] * wb[k + 3];
            }
            s_e[ln][0][wv * 4 + oo] = (p0 + p1) + (p2 + p3);
            s_e[ln][1][wv * 4 + oo] = (q0 + q1) + (q2 + q3);
        }
        __syncthreads();
        {
            const int col = tid & 15;
            const int lsub = tid >> 4;       // 0..15
            const int o = c4 * 16 + col;
            #pragma unroll
            for (int i = 0; i < 4; ++i) {
                const int e = lsub * 4 + i;
                const int ge = bb + e;
                const int sn = src[ge];
                const int dn = dst[ge];
                const float xs = xw[sn * HD + o];
                atomicAdd(&agg1[dn * HD + o], s_e[e][0][col] * xs);
                atomicAdd(&agg2[dn * HD + o], s_e[e][1][col] * xs);
            }
        }
        __syncthreads();
    }
}

// GraphNorm: one block per graph, batch[] sorted -> binary-search segment.
__global__ __launch_bounds__(128) void graphnorm_kernel(
    float* __restrict__ h, const int* __restrict__ batch,
    const float* __restrict__ nw, const float* __restrict__ nb,
    const float* __restrict__ nms, int n)
{
    const int b = blockIdx.x;
    const int j = threadIdx.x;
    int lo = 0, hi = n;
    while (lo < hi) { int m = (lo + hi) >> 1; if (batch[m] < b) lo = m + 1; else hi = m; }
    const int s = lo;
    hi = n;
    while (lo < hi) { int m = (lo + hi) >> 1; if (batch[m] <= b) lo = m + 1; else hi = m; }
    const int e = lo;
    if (e <= s) return;
    const float c = fmaxf((float)(e - s), 1.0f);
    float sum = 0.f;
    for (int nn = s; nn < e; ++nn) sum += h[nn * HD + j];
    const float mean = sum / c;
    const float mm = mean * nms[j];
    float var = 0.f;
    for (int nn = s; nn < e; ++nn) { float d = h[nn * HD + j] - mm; var += d * d; }
    const float inv = rsqrtf(var / c + 1e-5f);
    const float wj = nw[j], bj = nb[j];
    for (int nn = s; nn < e; ++nn) {
        float d = h[nn * HD + j] - mm;
        h[nn * HD + j] = wj * d * inv + bj;
    }
}

extern "C" void kernel_launch(void* const* d_in, const int* in_sizes, int n_in,
                              void* d_out, int out_size, void* d_ws, size_t ws_size,
                              hipStream_t stream)
{
    const float* x    = (const float*)d_in[0];
    const float* f1   = (const float*)d_in[1];
    const float* f2   = (const float*)d_in[2];
    const int*   eidx = (const int*)d_in[3];
    const int*   batch= (const int*)d_in[4];
    const float* linW = (const float*)d_in[5];
    const float* linb = (const float*)d_in[6];
    const float* f1W1 = (const float*)d_in[7];
    const float* f1W2 = (const float*)d_in[8];
    const float* f2W1 = (const float*)d_in[9];
    const float* f2W2 = (const float*)d_in[10];
    const float* c1rW = (const float*)d_in[11];
    const float* c1rb = (const float*)d_in[12];
    const float* c1oW = (const float*)d_in[13];
    const float* c2rW = (const float*)d_in[14];
    const float* c2rb = (const float*)d_in[15];
    const float* c2oW = (const float*)d_in[16];
    const float* l1W  = (const float*)d_in[17];
    const float* l1b  = (const float*)d_in[18];
    const float* l2W  = (const float*)d_in[19];
    const float* l2b  = (const float*)d_in[20];
    const float* catW = (const float*)d_in[21];
    const float* catb = (const float*)d_in[22];
    const float* nw   = (const float*)d_in[23];
    const float* nbb  = (const float*)d_in[24];
    const float* nms  = (const float*)d_in[25];
    const float* lsW  = (const float*)d_in[26];
    const float* lsb  = (const float*)d_in[27];
    const float* fW   = (const float*)d_in[28];
    const float* fb   = (const float*)d_in[29];

    const int N = NNODES;
    const size_t NM = (size_t)N * HD;
    float* ws   = (float*)d_ws;
    float* xw   = ws;
    float* agg1 = ws + 1 * NM;
    float* agg2 = ws + 2 * NM;
    float* t    = ws + 3 * NM;
    float* h1   = ws + 4 * NM;
    float* h2   = ws + 5 * NM;

    const int mmGrid = (N + 63) / 64;

    // x' = swish(x @ linW^T + linb)
    node_mm_kernel<<<mmGrid, 256, 0, stream>>>(x, linW, HD, linb, nullptr, xw, N, F_SWISH);

    // agg1, agg2 = 0 (contiguous)
    hipMemsetAsync(agg1, 0, 2 * NM * sizeof(float), stream);

    // fused edge MLPs + gather*feature + scatter-add
    edge_kernel<<<NEDGES / 64, 256, 0, stream>>>(f1, f2, eidx, eidx + NEDGES, xw,
                                                 f1W1, f1W2, f2W1, f2W2, agg1, agg2);

    // h1 = swish((agg1@rel1^T + b + xw@root1^T) @ l1W^T + l1b)
    node_mm_kernel<<<mmGrid, 256, 0, stream>>>(agg1, c1rW, HD, c1rb, nullptr, t, N, 0);
    node_mm_kernel<<<mmGrid, 256, 0, stream>>>(xw,   c1oW, HD, nullptr, nullptr, t, N, F_ACC);
    node_mm_kernel<<<mmGrid, 256, 0, stream>>>(t,    l1W,  HD, l1b, nullptr, h1, N, F_SWISH);

    // h2 likewise
    node_mm_kernel<<<mmGrid, 256, 0, stream>>>(agg2, c2rW, HD, c2rb, nullptr, t, N, 0);
    node_mm_kernel<<<mmGrid, 256, 0, stream>>>(xw,   c2oW, HD, nullptr, nullptr, t, N, F_ACC);
    node_mm_kernel<<<mmGrid, 256, 0, stream>>>(t,    l2W,  HD, l2b, nullptr, h2, N, F_SWISH);

    // h = [h1,h2] @ catW^T + catb + xw   (h lives in agg1, now free)
    node_mm_kernel<<<mmGrid, 256, 0, stream>>>(h1, catW,       256, catb, nullptr, agg1, N, 0);
    node_mm_kernel<<<mmGrid, 256, 0, stream>>>(h2, catW + HD,  256, nullptr, xw, agg1, N, F_ACC | F_RES);

    // 3x residual swish-linear, ping-pong agg1 <-> t
    node_mm_kernel<<<mmGrid, 256, 0, stream>>>(agg1, lsW + 0 * HD * HD, HD, lsb + 0 * HD, agg1, t,    N, F_SWISH | F_RES);
    node_mm_kernel<<<mmGrid, 256, 0, stream>>>(t,    lsW + 1 * HD * HD, HD, lsb + 1 * HD, t,    agg1, N, F_SWISH | F_RES);
    node_mm_kernel<<<mmGrid, 256, 0, stream>>>(agg1, lsW + 2 * HD * HD, HD, lsb + 2 * HD, agg1, t,    N, F_SWISH | F_RES);

    // GraphNorm (in place on t)
    graphnorm_kernel<<<NGRAPH, 128, 0, stream>>>(t, batch, nw, nbb, nms, N);

    // out = t @ fW^T + fb
    node_mm_kernel<<<mmGrid, 256, 0, stream>>>(t, fW, HD, fb, nullptr, (float*)d_out, N, 0);
}

// Round 3
// 3174.365 us; speedup vs baseline: 2.6799x; 2.6799x over previous
//
#include <hip/hip_runtime.h>
#include <math.h>

#define HD 128
#define NNODES 50000
#define NEDGES 1000000
#define NGRAPH 512

enum { F_ACC = 1, F_SWISH = 2, F_RES = 4 };

__device__ __forceinline__ float swish_f(float v) {
    return v / (1.0f + __expf(-v));
}

// out[n,o] = post( sum_k A[n,k] * W[o*wld+k] + bias[o] ), rows tiled 64/block.
// lane = row; wave w computes outputs [32w, 32w+32). Weight row index forced
// scalar via readfirstlane -> s_load on scalar pipe; float4 weight fetch.
__global__ __launch_bounds__(256) void node_mm_kernel(
    const float* __restrict__ A, const float* __restrict__ W, int wld,
    const float* __restrict__ bias, const float* __restrict__ res,
    float* __restrict__ out, int nrows, int flags)
{
    __shared__ float s_a[64 * 129];
    const int tid = threadIdx.x;
    const int ln = tid & 63;
    const int wv = tid >> 6;
    const int tile = blockIdx.x * 64;

    for (int i = tid; i < 64 * HD; i += 256) {
        int r = i >> 7, c = i & (HD - 1);
        int row = tile + r;
        if (row >= nrows) row = nrows - 1;
        s_a[r * 129 + c] = A[row * HD + c];
    }
    __syncthreads();

    const int o0 = __builtin_amdgcn_readfirstlane(wv * 32);
    float acc[32];
    #pragma unroll
    for (int oo = 0; oo < 32; ++oo) acc[oo] = 0.0f;

    for (int k = 0; k < HD; k += 4) {
        float a0 = s_a[ln * 129 + k + 0];
        float a1 = s_a[ln * 129 + k + 1];
        float a2 = s_a[ln * 129 + k + 2];
        float a3 = s_a[ln * 129 + k + 3];
        #pragma unroll
        for (int oo = 0; oo < 32; ++oo) {
            const float4 w4 = *(const float4*)(W + (size_t)(o0 + oo) * wld + k);
            acc[oo] += a0 * w4.x + a1 * w4.y + a2 * w4.z + a3 * w4.w;
        }
    }
    __syncthreads();
    #pragma unroll
    for (int oo = 0; oo < 32; ++oo) s_a[ln * 129 + o0 + oo] = acc[oo];
    __syncthreads();

    for (int i = tid; i < 64 * HD; i += 256) {
        int r = i >> 7, c = i & (HD - 1);
        int row = tile + r;
        if (row < nrows) {
            float v = s_a[r * 129 + c];
            if (bias) v += bias[c];
            if (flags & F_ACC) v += out[row * HD + c];
            if (flags & F_SWISH) v = swish_f(v);
            if (flags & F_RES) v += res[row * HD + c];
            out[row * HD + c] = v;
        }
    }
}

// ---------- CSR build: histogram -> exclusive scan -> scatter perm ----------
__global__ __launch_bounds__(256) void hist_kernel(
    const int* __restrict__ dst, int* __restrict__ cnt, int E)
{
    int e = blockIdx.x * 256 + threadIdx.x;
    if (e < E) atomicAdd(&cnt[dst[e]], 1);
}

__global__ __launch_bounds__(1024) void scan_kernel(
    const int* __restrict__ cnt, int* __restrict__ cur, int n)
{
    __shared__ int part[1024];
    const int t = threadIdx.x;
    const int chunk = (n + 1023) >> 10;
    const int s = t * chunk;
    const int e = min(s + chunk, n);
    int sum = 0;
    for (int i = s; i < e; ++i) sum += cnt[i];
    part[t] = sum;
    __syncthreads();
    for (int off = 1; off < 1024; off <<= 1) {
        int v = (t >= off) ? part[t - off] : 0;
        __syncthreads();
        part[t] += v;
        __syncthreads();
    }
    int base = part[t] - sum;   // exclusive prefix
    for (int i = s; i < e; ++i) { cur[i] = base; base += cnt[i]; }
}

__global__ __launch_bounds__(256) void scatter_kernel(
    const int* __restrict__ dst, int* __restrict__ cur,
    int* __restrict__ perm, int E)
{
    int e = blockIdx.x * 256 + threadIdx.x;
    if (e < E) {
        int p = atomicAdd(&cur[dst[e]], 1);
        perm[p] = e;
    }
}

// ---------- Fused edge pipeline over dst-sorted edges ----------
// 64 sorted edges/block. mids -> registers; per col-half {lo,hi}:
// msgs (both aggs) -> LDS, segmented reduce over sorted dst, coalesced
// atomic flush only at segment boundaries (~4-5 distinct dst per block).
__global__ __launch_bounds__(256) void edge_kernel(
    const float* __restrict__ feat1, const float* __restrict__ feat2,
    const int* __restrict__ src, const int* __restrict__ dst,
    const int* __restrict__ perm, const float* __restrict__ xw,
    const float* __restrict__ w1a, const float* __restrict__ w2a,
    const float* __restrict__ w1b, const float* __restrict__ w2b,
    float* __restrict__ agg1, float* __restrict__ agg2)
{
    __shared__ float s_f[64 * 73];     // feat1 cols 0..53, feat2 cols 54..71
    __shared__ float s_big[8320];      // mids (stride 129), then msgs (2*64*65)
    __shared__ int s_perm[64], s_src[64], s_dst[64];

    const int tid = threadIdx.x;
    const int ln = tid & 63;
    const int wv = tid >> 6;
    const int bb = blockIdx.x * 64;

    if (tid < 64) s_perm[tid] = perm[bb + tid];
    __syncthreads();
    if (tid < 64) {
        int e = s_perm[tid];
        s_src[tid] = src[e];
        s_dst[tid] = dst[e];
    }
    for (int i = tid; i < 64 * 54; i += 256) {
        int r = i / 54, c = i - r * 54;
        s_f[r * 73 + c] = feat1[(size_t)s_perm[r] * 54 + c];
    }
    for (int i = tid; i < 64 * 18; i += 256) {
        int r = i / 18, c = i - r * 18;
        s_f[r * 73 + 54 + c] = feat2[(size_t)s_perm[r] * 18 + c];
    }
    __syncthreads();

    // ---- mid phase: lane = edge; wave wv owns mid outputs [16wv,16wv+16)
    {
        const int o0 = __builtin_amdgcn_readfirstlane(wv * 16);
        const float* __restrict__ w1ap = w1a + (size_t)o0 * 54;
        const float* __restrict__ w1bp = w1b + (size_t)o0 * 18;
        float acc1[16], acc2[16];
        #pragma unroll
        for (int oo = 0; oo < 16; ++oo) { acc1[oo] = 0.f; acc2[oo] = 0.f; }
        for (int k = 0; k < 54; ++k) {
            float a = s_f[ln * 73 + k];
            #pragma unroll
            for (int oo = 0; oo < 16; ++oo)
                acc1[oo] += a * w1ap[oo * 54 + k];
        }
        for (int k = 0; k < 18; ++k) {
            float a = s_f[ln * 73 + 54 + k];
            #pragma unroll
            for (int oo = 0; oo < 16; ++oo)
                acc2[oo] += a * w1bp[oo * 18 + k];
        }
        #pragma unroll
        for (int oo = 0; oo < 16; ++oo) {
            s_big[ln * 129 + o0 + oo] = acc1[oo];
            s_big[ln * 129 + 64 + o0 + oo] = acc2[oo];
        }
    }
    __syncthreads();

    // ---- pull this lane's edge mids into registers
    float m1[64], m2[64];
    #pragma unroll
    for (int k = 0; k < 64; ++k) {
        m1[k] = s_big[ln * 129 + k];
        m2[k] = s_big[ln * 129 + 64 + k];
    }
    __syncthreads();   // s_big now reusable as msg buffer

    const int sn = s_src[ln];

    for (int hb = 0; hb < 2; ++hb) {
        const int colbase = hb * 64;
        const int ob = __builtin_amdgcn_readfirstlane(colbase + wv * 16);
        const float* __restrict__ w2ap = w2a + (size_t)ob * 64;
        const float* __restrict__ w2bp = w2b + (size_t)ob * 64;

        // xw factors for this thread's 16 cols (64B contiguous)
        float xwv[16];
        {
            const float* xr = xw + (size_t)sn * HD + colbase + wv * 16;
            #pragma unroll
            for (int q = 0; q < 4; ++q) {
                float4 v = *(const float4*)(xr + 4 * q);
                xwv[4 * q + 0] = v.x; xwv[4 * q + 1] = v.y;
                xwv[4 * q + 2] = v.z; xwv[4 * q + 3] = v.w;
            }
        }

        // msgs: msg[agg][c][e] at s_big[agg*4160 + c*65 + e]
        #pragma unroll
        for (int ag = 0; ag < 2; ++ag) {
            const float* __restrict__ wp = ag ? w2bp : w2ap;
            #pragma unroll
            for (int oo = 0; oo < 16; ++oo) {
                float d0 = 0, d1 = 0, d2 = 0, d3 = 0;
                #pragma unroll
                for (int k = 0; k < 64; k += 4) {
                    float a0 = ag ? m2[k + 0] : m1[k + 0];
                    float a1 = ag ? m2[k + 1] : m1[k + 1];
                    float a2 = ag ? m2[k + 2] : m1[k + 2];
                    float a3 = ag ? m2[k + 3] : m1[k + 3];
                    d0 += a0 * wp[oo * 64 + k + 0];
                    d1 += a1 * wp[oo * 64 + k + 1];
                    d2 += a2 * wp[oo * 64 + k + 2];
                    d3 += a3 * wp[oo * 64 + k + 3];
                }
                s_big[ag * 4160 + (wv * 16 + oo) * 65 + ln] =
                    ((d0 + d1) + (d2 + d3)) * xwv[oo];
            }
        }
        __syncthreads();

        // segmented reduction over sorted dst; flush at boundaries
        if (tid < 128) {
            const int ag = tid >> 6;
            const int c = tid & 63;
            float* __restrict__ aggp = ag ? agg2 : agg1;
            const int base = ag * 4160 + c * 65;
            float sum = 0.f;
            for (int e = 0; e < 64; ++e) {
                sum += s_big[base + e];
                if (e == 63 || s_dst[e] != s_dst[e + 1]) {
                    atomicAdd(&aggp[(size_t)s_dst[e] * HD + colbase + c], sum);
                    sum = 0.f;
                }
            }
        }
        __syncthreads();
    }
}

// GraphNorm: one block per graph, batch[] sorted -> binary-search segment.
__global__ __launch_bounds__(128) void graphnorm_kernel(
    float* __restrict__ h, const int* __restrict__ batch,
    const float* __restrict__ nw, const float* __restrict__ nb,
    const float* __restrict__ nms, int n)
{
    const int b = blockIdx.x;
    const int j = threadIdx.x;
    int lo = 0, hi = n;
    while (lo < hi) { int m = (lo + hi) >> 1; if (batch[m] < b) lo = m + 1; else hi = m; }
    const int s = lo;
    hi = n;
    while (lo < hi) { int m = (lo + hi) >> 1; if (batch[m] <= b) lo = m + 1; else hi = m; }
    const int e = lo;
    if (e <= s) return;
    const float c = fmaxf((float)(e - s), 1.0f);
    float sum = 0.f;
    for (int nn = s; nn < e; ++nn) sum += h[nn * HD + j];
    const float mean = sum / c;
    const float mm = mean * nms[j];
    float var = 0.f;
    for (int nn = s; nn < e; ++nn) { float d = h[nn * HD + j] - mm; var += d * d; }
    const float inv = rsqrtf(var / c + 1e-5f);
    const float wj = nw[j], bj = nb[j];
    for (int nn = s; nn < e; ++nn) {
        float d = h[nn * HD + j] - mm;
        h[nn * HD + j] = wj * d * inv + bj;
    }
}

extern "C" void kernel_launch(void* const* d_in, const int* in_sizes, int n_in,
                              void* d_out, int out_size, void* d_ws, size_t ws_size,
                              hipStream_t stream)
{
    const float* x    = (const float*)d_in[0];
    const float* f1   = (const float*)d_in[1];
    const float* f2   = (const float*)d_in[2];
    const int*   eidx = (const int*)d_in[3];
    const int*   batch= (const int*)d_in[4];
    const float* linW = (const float*)d_in[5];
    const float* linb = (const float*)d_in[6];
    const float* f1W1 = (const float*)d_in[7];
    const float* f1W2 = (const float*)d_in[8];
    const float* f2W1 = (const float*)d_in[9];
    const float* f2W2 = (const float*)d_in[10];
    const float* c1rW = (const float*)d_in[11];
    const float* c1rb = (const float*)d_in[12];
    const float* c1oW = (const float*)d_in[13];
    const float* c2rW = (const float*)d_in[14];
    const float* c2rb = (const float*)d_in[15];
    const float* c2oW = (const float*)d_in[16];
    const float* l1W  = (const float*)d_in[17];
    const float* l1b  = (const float*)d_in[18];
    const float* l2W  = (const float*)d_in[19];
    const float* l2b  = (const float*)d_in[20];
    const float* catW = (const float*)d_in[21];
    const float* catb = (const float*)d_in[22];
    const float* nw   = (const float*)d_in[23];
    const float* nbb  = (const float*)d_in[24];
    const float* nms  = (const float*)d_in[25];
    const float* lsW  = (const float*)d_in[26];
    const float* lsb  = (const float*)d_in[27];
    const float* fW   = (const float*)d_in[28];
    const float* fb   = (const float*)d_in[29];

    const int N = NNODES;
    const size_t NM = (size_t)N * HD;
    float* ws   = (float*)d_ws;
    float* xw   = ws;
    float* agg1 = ws + 1 * NM;
    float* agg2 = ws + 2 * NM;
    float* t    = ws + 3 * NM;
    float* h1   = ws + 4 * NM;
    float* h2   = ws + 5 * NM;

    // CSR scratch overlays h1 (h1 is only written AFTER edge_kernel finishes)
    int* perm = (int*)h1;                 // NEDGES ints
    int* cnt  = perm + NEDGES;            // NNODES ints
    int* cur  = cnt + NNODES;             // NNODES ints

    const int*  esrc = eidx;
    const int*  edst = eidx + NEDGES;
    const int mmGrid = (N + 63) / 64;

    // x' = swish(x @ linW^T + linb)
    node_mm_kernel<<<mmGrid, 256, 0, stream>>>(x, linW, HD, linb, nullptr, xw, N, F_SWISH);

    // zero aggs + histogram counters
    hipMemsetAsync(agg1, 0, 2 * NM * sizeof(float), stream);
    hipMemsetAsync(cnt, 0, NNODES * sizeof(int), stream);

    // build dst-sorted edge permutation
    hist_kernel<<<(NEDGES + 255) / 256, 256, 0, stream>>>(edst, cnt, NEDGES);
    scan_kernel<<<1, 1024, 0, stream>>>(cnt, cur, NNODES);
    scatter_kernel<<<(NEDGES + 255) / 256, 256, 0, stream>>>(edst, cur, perm, NEDGES);

    // fused edge MLPs + gather*feature + segmented scatter-add
    edge_kernel<<<NEDGES / 64, 256, 0, stream>>>(f1, f2, esrc, edst, perm, xw,
                                                 f1W1, f1W2, f2W1, f2W2, agg1, agg2);

    // h1 = swish((agg1@rel1^T + b + xw@root1^T) @ l1W^T + l1b)
    node_mm_kernel<<<mmGrid, 256, 0, stream>>>(agg1, c1rW, HD, c1rb, nullptr, t, N, 0);
    node_mm_kernel<<<mmGrid, 256, 0, stream>>>(xw,   c1oW, HD, nullptr, nullptr, t, N, F_ACC);
    node_mm_kernel<<<mmGrid, 256, 0, stream>>>(t,    l1W,  HD, l1b, nullptr, h1, N, F_SWISH);

    // h2 likewise
    node_mm_kernel<<<mmGrid, 256, 0, stream>>>(agg2, c2rW, HD, c2rb, nullptr, t, N, 0);
    node_mm_kernel<<<mmGrid, 256, 0, stream>>>(xw,   c2oW, HD, nullptr, nullptr, t, N, F_ACC);
    node_mm_kernel<<<mmGrid, 256, 0, stream>>>(t,    l2W,  HD, l2b, nullptr, h2, N, F_SWISH);

    // h = [h1,h2] @ catW^T + catb + xw   (h lives in agg1, now free)
    node_mm_kernel<<<mmGrid, 256, 0, stream>>>(h1, catW,       256, catb, nullptr, agg1, N, 0);
    node_mm_kernel<<<mmGrid, 256, 0, stream>>>(h2, catW + HD,  256, nullptr, xw, agg1, N, F_ACC | F_RES);

    // 3x residual swish-linear, ping-pong agg1 <-> t
    node_mm_kernel<<<mmGrid, 256, 0, stream>>>(agg1, lsW + 0 * HD * HD, HD, lsb + 0 * HD, agg1, t,    N, F_SWISH | F_RES);
    node_mm_kernel<<<mmGrid, 256, 0, stream>>>(t,    lsW + 1 * HD * HD, HD, lsb + 1 * HD, t,    agg1, N, F_SWISH | F_RES);
    node_mm_kernel<<<mmGrid, 256, 0, stream>>>(agg1, lsW + 2 * HD * HD, HD, lsb + 2 * HD, agg1, t,    N, F_SWISH | F_RES);

    // GraphNorm (in place on t)
    graphnorm_kernel<<<NGRAPH, 128, 0, stream>>>(t, batch, nw, nbb, nms, N);

    // out = t @ fW^T + fb
    node_mm_kernel<<<mmGrid, 256, 0, stream>>>(t, fW, HD, fb, nullptr, (float*)d_out, N, 0);
}